// Round 9
// baseline (144.759 us; speedup 1.0000x reference)
//
#include <hip/hip_runtime.h>
#include <hip/hip_bf16.h>

typedef unsigned short u16;
typedef unsigned int u32;
typedef __bf16 bf16x8_t __attribute__((ext_vector_type(8)));
typedef float f32x4_t __attribute__((ext_vector_type(4)));

constexpr int Bb = 4;
constexpr int Tt = 4096;
constexpr int Dd = 64;
constexpr int NQT  = Tt / 64;              // 64 q-tiles (64 rows) per batch
constexpr int NTRI = NQT * (NQT + 1) / 2;  // 2080 causal tiles per batch
constexpr float QSCALE = 0.18033688011112042f; // 0.125 * log2(e), folded into q

__device__ __forceinline__ u16 f2bf(float f) {
  unsigned int u = __builtin_bit_cast(unsigned int, f);
  return (u16)((u + 0x7fffu + ((u >> 16) & 1u)) >> 16);
}
__device__ __forceinline__ u32 pk2(float a, float b) {
  return (u32)f2bf(a) | ((u32)f2bf(b) << 16);
}
__device__ __forceinline__ bf16x8_t ld16(const u16* p) {
  int4 v = *(const int4*)p;
  return __builtin_bit_cast(bf16x8_t, v);
}
__device__ __forceinline__ bf16x8_t cvtld8(const float* p) {
  float4 a = ((const float4*)p)[0];
  float4 b = ((const float4*)p)[1];
  union { u32 u[4]; bf16x8_t v; } r;
  r.u[0] = pk2(a.x, a.y); r.u[1] = pk2(a.z, a.w);
  r.u[2] = pk2(b.x, b.y); r.u[3] = pk2(b.z, b.w);
  return r.v;
}
__device__ __forceinline__ f32x4_t mfma16(bf16x8_t a, bf16x8_t b, f32x4_t c) {
  return __builtin_amdgcn_mfma_f32_16x16x32_bf16(a, b, c, 0, 0, 0);
}

// ---------------- proj: grid (256,3) — one output matrix per blockIdx.y ----------------
__global__ __launch_bounds__(256) void HeadV1_proj(
    const float* __restrict__ x, const float* __restrict__ Wk,
    const float* __restrict__ Wq, const float* __restrict__ Wv,
    u16* __restrict__ qo, u16* __restrict__ ko, u16* __restrict__ vTo)
{
  const int t = threadIdx.x;
  const int w = t >> 6, lane = t & 63, l15 = lane & 15, quad = lane >> 4;
  const int row0 = blockIdx.x * 64 + w * 16;
  const int b = row0 >> 12, rloc0 = row0 & 4095;
  const int m = blockIdx.y;

  bf16x8_t xf[2];
  #pragma unroll
  for (int kh = 0; kh < 2; kh++)
    xf[kh] = cvtld8(x + (long)(row0 + l15) * 64 + kh * 32 + quad * 8);

  const float* W = (m == 0) ? Wk : (m == 1) ? Wq : Wv;
  #pragma unroll
  for (int g = 0; g < 4; g++) {
    f32x4_t acc = {0.f, 0.f, 0.f, 0.f};
    #pragma unroll
    for (int kh = 0; kh < 2; kh++) {
      bf16x8_t wf = cvtld8(W + (g * 16 + l15) * 64 + kh * 32 + quad * 8);
      acc = mfma16(xf[kh], wf, acc);
    }
    if (m == 0) {
      #pragma unroll
      for (int r = 0; r < 4; r++)
        ko[(long)(row0 + quad * 4 + r) * 64 + g * 16 + l15] = f2bf(acc[r]);
    } else if (m == 1) {
      #pragma unroll
      for (int r = 0; r < 4; r++)
        qo[(long)(row0 + quad * 4 + r) * 64 + g * 16 + l15] = f2bf(acc[r] * QSCALE);
    } else {
      #pragma unroll
      for (int r = 0; r < 4; r++)
        vTo[((long)b * 64 + g * 16 + l15) * Tt + rloc0 + quad * 4 + r] = f2bf(acc[r]);
    }
  }
}

// ---------------- k1: P = exp2(S^T) per causal 64x64 tile ----------------
// 8320 blocks (b, tri-idx). Wave w owns q-strip w*16. P stored bf16, packed causal:
// region = ((b*NTRI + idx) * 4096) u16, layout [q 64][kv 64] — exactly k2's B-frag rows.
__global__ __launch_bounds__(256) void HeadV1_scores(
    const u16* __restrict__ qg, const u16* __restrict__ kg, u16* __restrict__ Pg)
{
  const int t = threadIdx.x;
  const int w = t >> 6, lane = t & 63, l15 = lane & 15, quad = lane >> 4;
  const int b   = blockIdx.x & 3;
  const int idx = blockIdx.x >> 2;                 // 0..2079
  int qt = (int)((sqrtf(8.f * idx + 1.f) - 1.f) * 0.5f);
  while ((qt + 1) * (qt + 2) / 2 <= idx) qt++;
  while (qt * (qt + 1) / 2 > idx) qt--;
  const int kvt = idx - qt * (qt + 1) / 2;

  const long base = (long)b * Tt * Dd;
  const int q0  = qt * 64 + w * 16;                // wave's q strip
  const int kv0 = kvt * 64;
  const bool diag = (qt == kvt);

  bf16x8_t qfrag[2];
  #pragma unroll
  for (int kk = 0; kk < 2; kk++)
    qfrag[kk] = ld16(qg + base + (long)(q0 + l15) * 64 + kk * 32 + quad * 8);

  u16* regp = Pg + ((long)b * NTRI + idx) * 4096;

  #pragma unroll
  for (int rt = 0; rt < 4; rt++) {
    bf16x8_t k0 = ld16(kg + base + (long)(kv0 + rt * 16 + l15) * 64 + 0  + quad * 8);
    bf16x8_t k1 = ld16(kg + base + (long)(kv0 + rt * 16 + l15) * 64 + 32 + quad * 8);
    f32x4_t acc = {0.f, 0.f, 0.f, 0.f};
    acc = mfma16(k0, qfrag[0], acc);
    acc = mfma16(k1, qfrag[1], acc);
    if (diag) {
      const int kvl = rt * 16 + quad * 4;          // local kv of acc[0]
      const int ql  = w * 16 + l15;                // local q
      #pragma unroll
      for (int r = 0; r < 4; r++)
        if (kvl + r > ql) acc[r] = -1e30f;         // exp2 -> 0
    }
    const float p0 = exp2f(acc[0]), p1 = exp2f(acc[1]);
    const float p2 = exp2f(acc[2]), p3 = exp2f(acc[3]);
    uint2 pk;
    pk.x = pk2(p0, p1);
    pk.y = pk2(p2, p3);
    *(uint2*)(regp + (w * 16 + l15) * 64 + rt * 16 + quad * 4) = pk;
  }
}

// ---------------- k2: O^T = V^T * P^T, l via all-ones A-fragment MFMA ----------------
// 512 blocks: b=blk&3, u=blk>>2, j = u<64?u:191-u (q-tile-32; pairs sum to constant work).
// 4 waves split kv tiles by parity; LDS chunked merge; fp32 output.
__global__ __launch_bounds__(256) void HeadV1_pv(
    const u16* __restrict__ vTg, const u16* __restrict__ Pg, float* __restrict__ outg)
{
  __shared__ float chk[4][16][33];
  __shared__ float stg[32][68];
  __shared__ float lst[4][32];

  const int t = threadIdx.x;
  const int w = t >> 6, lane = t & 63, l15 = lane & 15, quad = lane >> 4;
  const int b = blockIdx.x & 3;
  const int u = blockIdx.x >> 2;            // 0..127
  const int j = (u < 64) ? u : (191 - u);   // q-tile-32 index
  const int qt  = j >> 1;
  const int ql0 = (j & 1) * 32;             // q offset inside the 64-q P region
  const int qr0 = j * 32;
  const long base = (long)b * Tt * Dd;

  union { u32 u4[4]; bf16x8_t v; } uo;
  uo.u4[0] = uo.u4[1] = uo.u4[2] = uo.u4[3] = 0x3F803F80u; // bf16 1.0 x8
  const bf16x8_t ones = uo.v;

  const f32x4_t zero4 = {0.f, 0.f, 0.f, 0.f};
  f32x4_t O[4][2];
  #pragma unroll
  for (int a = 0; a < 4; a++)
    #pragma unroll
    for (int c = 0; c < 2; c++)
      O[a][c] = zero4;
  f32x4_t Lc[2] = {zero4, zero4};

  const int nk = qt + 1;
  const u16* Pb = Pg + ((long)b * NTRI + (long)qt * (qt + 1) / 2) * 4096;

  for (int kt = w; kt < nk; kt += 4) {
    const u16* reg = Pb + (long)kt * 4096;
    bf16x8_t pf[2][2];
    #pragma unroll
    for (int ct = 0; ct < 2; ct++)
      #pragma unroll
      for (int kkv = 0; kkv < 2; kkv++)
        pf[ct][kkv] = ld16(reg + (ql0 + ct * 16 + l15) * 64 + kkv * 32 + quad * 8);

    #pragma unroll
    for (int kkv = 0; kkv < 2; kkv++) {
      #pragma unroll
      for (int dt = 0; dt < 4; dt++) {
        bf16x8_t vf = ld16(vTg + ((long)b * 64 + dt * 16 + l15) * Tt + kt * 64 + kkv * 32 + quad * 8);
        #pragma unroll
        for (int ct = 0; ct < 2; ct++)
          O[dt][ct] = mfma16(vf, pf[ct][kkv], O[dt][ct]);
      }
      #pragma unroll
      for (int ct = 0; ct < 2; ct++)
        Lc[ct] = mfma16(ones, pf[ct][kkv], Lc[ct]);  // C[m][q] = l[q] for all m
    }
  }

  if (quad == 0) {
    #pragma unroll
    for (int ct = 0; ct < 2; ct++)
      lst[w][ct * 16 + l15] = Lc[ct][0];
  }
  __syncthreads();

  #pragma unroll
  for (int drt = 0; drt < 4; drt++) {
    #pragma unroll
    for (int ct = 0; ct < 2; ct++)
      #pragma unroll
      for (int r = 0; r < 4; r++)
        chk[w][quad * 4 + r][ct * 16 + l15] = O[drt][ct][r];
    __syncthreads();
    #pragma unroll
    for (int h = 0; h < 2; h++) {
      const int pos = t + h * 256;
      const int d2 = pos >> 5, q = pos & 31;
      stg[q][drt * 16 + d2] = ((chk[0][d2][q] + chk[1][d2][q]) + (chk[2][d2][q] + chk[3][d2][q]));
    }
    __syncthreads();
  }

  { // normalize + coalesced fp32 write: thread -> (q = t>>3, d0 = (t&7)*8)
    const int q = t >> 3, d0 = (t & 7) * 8;
    const float L = (lst[0][q] + lst[1][q]) + (lst[2][q] + lst[3][q]);
    const float invL = 1.0f / L;
    float ov[8];
    #pragma unroll
    for (int i = 0; i < 8; i++) ov[i] = stg[q][d0 + i] * invL;
    float* dst = outg + base + (long)(qr0 + q) * 64 + d0;
    *(float4*)dst       = *(const float4*)&ov[0];
    *(float4*)(dst + 4) = *(const float4*)&ov[4];
  }
}

extern "C" void kernel_launch(void* const* d_in, const int* in_sizes, int n_in,
                              void* d_out, int out_size, void* d_ws, size_t ws_size,
                              hipStream_t stream) {
  (void)in_sizes; (void)n_in; (void)out_size; (void)ws_size;
  const float* x  = (const float*)d_in[0];
  const float* Wk = (const float*)d_in[1];
  const float* Wq = (const float*)d_in[2];
  const float* Wv = (const float*)d_in[3];
  float* out = (float*)d_out;
  // workspace: q 2MB | k 2MB | vT 2MB | P packed-causal bf16 68MB
  u16* qw  = (u16*)d_ws;
  u16* kw  = qw + (size_t)Bb * Tt * Dd;
  u16* vTw = kw + (size_t)Bb * Tt * Dd;
  u16* Pw  = vTw + (size_t)Bb * Tt * Dd;

  HeadV1_proj<<<dim3((Bb * Tt) / 64, 3), 256, 0, stream>>>(x, Wk, Wq, Wv, qw, kw, vTw);
  HeadV1_scores<<<Bb * NTRI, 256, 0, stream>>>(qw, kw, Pw);
  HeadV1_pv<<<512, 256, 0, stream>>>(vTw, Pw, out);
}

// Round 10
// 135.357 us; speedup vs baseline: 1.0695x; 1.0695x over previous
//
#include <hip/hip_runtime.h>
#include <hip/hip_bf16.h>

typedef unsigned short u16;
typedef unsigned int u32;
typedef __bf16 bf16x8_t __attribute__((ext_vector_type(8)));
typedef float f32x4_t __attribute__((ext_vector_type(4)));

constexpr int Bb = 4;
constexpr int Tt = 4096;
constexpr int Dd = 64;
constexpr float QSCALE = 0.18033688011112042f; // 0.125 * log2(e), folded into q

__device__ __forceinline__ u16 f2bf(float f) {
  unsigned int u = __builtin_bit_cast(unsigned int, f);
  return (u16)((u + 0x7fffu + ((u >> 16) & 1u)) >> 16);
}
__device__ __forceinline__ u32 pk2(float a, float b) {
  return (u32)f2bf(a) | ((u32)f2bf(b) << 16);
}
__device__ __forceinline__ bf16x8_t ld16(const u16* p) {
  int4 v = *(const int4*)p;
  return __builtin_bit_cast(bf16x8_t, v);
}
__device__ __forceinline__ bf16x8_t cvtld8(const float* p) {
  float4 a = ((const float4*)p)[0];
  float4 b = ((const float4*)p)[1];
  union { u32 u[4]; bf16x8_t v; } r;
  r.u[0] = pk2(a.x, a.y); r.u[1] = pk2(a.z, a.w);
  r.u[2] = pk2(b.x, b.y); r.u[3] = pk2(b.z, b.w);
  return r.v;
}
__device__ __forceinline__ f32x4_t mfma16(bf16x8_t a, bf16x8_t b, f32x4_t c) {
  return __builtin_amdgcn_mfma_f32_16x16x32_bf16(a, b, c, 0, 0, 0);
}

// ---------------- proj: grid (256,3) — one output matrix per blockIdx.y ----------------
__global__ __launch_bounds__(256) void HeadV1_proj(
    const float* __restrict__ x, const float* __restrict__ Wk,
    const float* __restrict__ Wq, const float* __restrict__ Wv,
    u16* __restrict__ qo, u16* __restrict__ ko, u16* __restrict__ vTo)
{
  const int t = threadIdx.x;
  const int w = t >> 6, lane = t & 63, l15 = lane & 15, quad = lane >> 4;
  const int row0 = blockIdx.x * 64 + w * 16;
  const int b = row0 >> 12, rloc0 = row0 & 4095;
  const int m = blockIdx.y;

  bf16x8_t xf[2];
  #pragma unroll
  for (int kh = 0; kh < 2; kh++)
    xf[kh] = cvtld8(x + (long)(row0 + l15) * 64 + kh * 32 + quad * 8);

  const float* W = (m == 0) ? Wk : (m == 1) ? Wq : Wv;
  #pragma unroll
  for (int g = 0; g < 4; g++) {
    f32x4_t acc = {0.f, 0.f, 0.f, 0.f};
    #pragma unroll
    for (int kh = 0; kh < 2; kh++) {
      bf16x8_t wf = cvtld8(W + (g * 16 + l15) * 64 + kh * 32 + quad * 8);
      acc = mfma16(xf[kh], wf, acc);
    }
    if (m == 0) {
      #pragma unroll
      for (int r = 0; r < 4; r++)
        ko[(long)(row0 + quad * 4 + r) * 64 + g * 16 + l15] = f2bf(acc[r]);
    } else if (m == 1) {
      #pragma unroll
      for (int r = 0; r < 4; r++)
        qo[(long)(row0 + quad * 4 + r) * 64 + g * 16 + l15] = f2bf(acc[r] * QSCALE);
    } else {
      #pragma unroll
      for (int r = 0; r < 4; r++)
        vTo[((long)b * 64 + g * 16 + l15) * Tt + rloc0 + quad * 4 + r] = f2bf(acc[r]);
    }
  }
}

// ---------------- flash v4: 16-q strips, in-block pairing, 8-wave kv-parity ----------------
// 512 blocks: b = blk&3, pp = blk>>2 (0..127). Two phases: strips s = pp and s = 255-pp
// (rows 16s..16s+15). nk(s) = s/4+1 kv-tiles of 64 -> 65 tiles/block, exactly balanced,
// no scheduler assumptions. 8 waves split kv tiles by parity. vf hoisted to tile top.
// l via ones-MFMA. No max-subtraction (scores bounded, exp2-domain |S| <~ 4).
// LDS: pT [8][16][72]u16 (18432) + lst [8][16]f32 @18432; merge overlays pT:
// chk [8][16][17]f32 @0 (8704), stg [16][68]f32 @8704 (4352).
__global__ __launch_bounds__(512, 4) void HeadV1_flash(
    const u16* __restrict__ qg, const u16* __restrict__ kg,
    const u16* __restrict__ vTg, float* __restrict__ outg)
{
  __shared__ __align__(16) char smem[18944];
  u16  (*pT)[16][72]   = (u16 (*)[16][72])smem;
  float (*chk)[16][17] = (float (*)[16][17])smem;
  float (*stg)[68]     = (float (*)[68])(smem + 8704);
  float (*lst)[16]     = (float (*)[16])(smem + 18432);

  const int t    = threadIdx.x;
  const int w    = t >> 6;        // 0..7
  const int lane = t & 63;
  const int l15  = lane & 15;
  const int quad = lane >> 4;

  const int b  = blockIdx.x & 3;
  const int pp = blockIdx.x >> 2;           // 0..127
  const long base = (long)b * Tt * Dd;

  union { u32 u4[4]; bf16x8_t v; } uo;
  uo.u4[0] = uo.u4[1] = uo.u4[2] = uo.u4[3] = 0x3F803F80u; // bf16 1.0 x8
  const bf16x8_t ones = uo.v;
  const f32x4_t zero4 = {0.f, 0.f, 0.f, 0.f};

  for (int ph = 0; ph < 2; ph++) {
    const int s   = ph ? (255 - pp) : pp;   // 16-row strip index
    const int qr0 = s * 16;
    const int nk  = (s >> 2) + 1;

    if (ph) __syncthreads();  // protect pT reuse vs prior phase's merge reads

    bf16x8_t qfrag[2];
    #pragma unroll
    for (int kk = 0; kk < 2; kk++)
      qfrag[kk] = ld16(qg + base + (long)(qr0 + l15) * 64 + kk * 32 + quad * 8);

    f32x4_t O[4];
    #pragma unroll
    for (int a = 0; a < 4; a++) O[a] = zero4;
    f32x4_t Lc = zero4;

    for (int kt = w; kt < nk; kt += 8) {
      const int kv0 = kt * 64;
      const bool ismask = (kt == nk - 1);

      // all global loads for this tile issue up front (k + v overlap QK/exp2)
      bf16x8_t kfrag[4][2];
      #pragma unroll
      for (int rt = 0; rt < 4; rt++)
        #pragma unroll
        for (int kk = 0; kk < 2; kk++)
          kfrag[rt][kk] = ld16(kg + base + (long)(kv0 + rt * 16 + l15) * 64 + kk * 32 + quad * 8);
      bf16x8_t vf[2][4];
      #pragma unroll
      for (int kk = 0; kk < 2; kk++)
        #pragma unroll
        for (int dt = 0; dt < 4; dt++)
          vf[kk][dt] = ld16(vTg + ((long)b * 64 + dt * 16 + l15) * Tt + kv0 + kk * 32 + quad * 8);

      // S^T[kv][q], exp2 units
      f32x4_t S[4];
      #pragma unroll
      for (int rt = 0; rt < 4; rt++) {
        f32x4_t acc = zero4;
        acc = mfma16(kfrag[rt][0], qfrag[0], acc);
        acc = mfma16(kfrag[rt][1], qfrag[1], acc);
        S[rt] = acc;
      }

      if (ismask) {
        const int qi = qr0 + l15;
        #pragma unroll
        for (int rt = 0; rt < 4; rt++) {
          const int kvb = kv0 + rt * 16 + quad * 4;
          #pragma unroll
          for (int r = 0; r < 4; r++)
            if (kvb + r > qi) S[rt][r] = -1e30f;  // exp2 -> 0
        }
      }

      // p = exp2(S) -> bf16 pT (per-wave region, no barrier)
      #pragma unroll
      for (int rt = 0; rt < 4; rt++) {
        const float p0 = exp2f(S[rt][0]);
        const float p1 = exp2f(S[rt][1]);
        const float p2 = exp2f(S[rt][2]);
        const float p3 = exp2f(S[rt][3]);
        uint2 pk;
        pk.x = pk2(p0, p1);
        pk.y = pk2(p2, p3);
        *(uint2*)&pT[w][l15][rt * 16 + quad * 4] = pk;
      }

      // O^T += V^T * P^T ; l += ones * P^T (row 0 of C = full kv-sum per q)
      #pragma unroll
      for (int kk = 0; kk < 2; kk++) {
        bf16x8_t pf = ld16(&pT[w][l15][kk * 32 + quad * 8]);
        #pragma unroll
        for (int dt = 0; dt < 4; dt++)
          O[dt] = mfma16(vf[kk][dt], pf, O[dt]);
        Lc = mfma16(ones, pf, Lc);
      }
    }

    // ---- 8-wave merge for this phase ----
    if (quad == 0) lst[w][l15] = Lc[0];
    __syncthreads();  // pT dead; chk/stg overlay it

    #pragma unroll
    for (int drt = 0; drt < 4; drt++) {
      #pragma unroll
      for (int r = 0; r < 4; r++)
        chk[w][quad * 4 + r][l15] = O[drt][r];
      __syncthreads();
      if (t < 256) {
        const int d2 = t >> 4, q = t & 15;
        float sum = 0.f;
        #pragma unroll
        for (int w2 = 0; w2 < 8; w2++) sum += chk[w2][d2][q];
        stg[q][drt * 16 + d2] = sum;
      }
      __syncthreads();
    }

    if (t < 256) { // normalize + coalesced fp32 write: 16 q x 64 d
      const int q = t >> 4, dg = t & 15;
      float L = 0.f;
      #pragma unroll
      for (int w2 = 0; w2 < 8; w2++) L += lst[w2][q];
      const float invL = 1.0f / L;
      float4 v = *(const float4*)&stg[q][dg * 4];
      v.x *= invL; v.y *= invL; v.z *= invL; v.w *= invL;
      *(float4*)(outg + base + (long)(qr0 + q) * 64 + dg * 4) = v;
    }
  }
}

extern "C" void kernel_launch(void* const* d_in, const int* in_sizes, int n_in,
                              void* d_out, int out_size, void* d_ws, size_t ws_size,
                              hipStream_t stream) {
  (void)in_sizes; (void)n_in; (void)out_size; (void)ws_size;
  const float* x  = (const float*)d_in[0];
  const float* Wk = (const float*)d_in[1];
  const float* Wq = (const float*)d_in[2];
  const float* Wv = (const float*)d_in[3];
  float* out = (float*)d_out;
  // workspace: q 2MB | k 2MB | vT 2MB
  u16* qw  = (u16*)d_ws;
  u16* kw  = qw + (size_t)Bb * Tt * Dd;
  u16* vTw = kw + (size_t)Bb * Tt * Dd;

  HeadV1_proj<<<dim3((Bb * Tt) / 64, 3), 256, 0, stream>>>(x, Wk, Wq, Wv, qw, kw, vTw);
  HeadV1_flash<<<512, 512, 0, stream>>>(qw, kw, vTw, out);
}

// Round 11
// 106.557 us; speedup vs baseline: 1.3585x; 1.2703x over previous
//
#include <hip/hip_runtime.h>
#include <hip/hip_bf16.h>

typedef unsigned short u16;
typedef unsigned int u32;
typedef __bf16 bf16x8_t __attribute__((ext_vector_type(8)));
typedef float f32x4_t __attribute__((ext_vector_type(4)));

constexpr int Bb = 4;
constexpr int Tt = 4096;
constexpr int Dd = 64;
constexpr float QSCALE = 0.18033688011112042f; // 0.125 * log2(e), folded into q

__device__ __forceinline__ u16 f2bf(float f) { // RNE (proj outputs)
  unsigned int u = __builtin_bit_cast(unsigned int, f);
  return (u16)((u + 0x7fffu + ((u >> 16) & 1u)) >> 16);
}
__device__ __forceinline__ u32 pk2(float a, float b) { // RNE pack
  return (u32)f2bf(a) | ((u32)f2bf(b) << 16);
}
__device__ __forceinline__ u32 pkt(float a, float b) { // truncation pack (3 inst)
  const u32 ua = __builtin_bit_cast(u32, a);
  const u32 ub = __builtin_bit_cast(u32, b);
  return (ua >> 16) | (ub & 0xFFFF0000u);
}
__device__ __forceinline__ bf16x8_t ld16(const u16* p) {
  int4 v = *(const int4*)p;
  return __builtin_bit_cast(bf16x8_t, v);
}
__device__ __forceinline__ bf16x8_t cvtld8(const float* p) {
  float4 a = ((const float4*)p)[0];
  float4 b = ((const float4*)p)[1];
  union { u32 u[4]; bf16x8_t v; } r;
  r.u[0] = pk2(a.x, a.y); r.u[1] = pk2(a.z, a.w);
  r.u[2] = pk2(b.x, b.y); r.u[3] = pk2(b.z, b.w);
  return r.v;
}
__device__ __forceinline__ f32x4_t mfma16(bf16x8_t a, bf16x8_t b, f32x4_t c) {
  return __builtin_amdgcn_mfma_f32_16x16x32_bf16(a, b, c, 0, 0, 0);
}

// ---------------- proj: grid (256,3) — one output matrix per blockIdx.y ----------------
__global__ __launch_bounds__(256) void HeadV1_proj(
    const float* __restrict__ x, const float* __restrict__ Wk,
    const float* __restrict__ Wq, const float* __restrict__ Wv,
    u16* __restrict__ qo, u16* __restrict__ ko, u16* __restrict__ vTo)
{
  const int t = threadIdx.x;
  const int w = t >> 6, lane = t & 63, l15 = lane & 15, quad = lane >> 4;
  const int row0 = blockIdx.x * 64 + w * 16;
  const int b = row0 >> 12, rloc0 = row0 & 4095;
  const int m = blockIdx.y;

  bf16x8_t xf[2];
  #pragma unroll
  for (int kh = 0; kh < 2; kh++)
    xf[kh] = cvtld8(x + (long)(row0 + l15) * 64 + kh * 32 + quad * 8);

  const float* W = (m == 0) ? Wk : (m == 1) ? Wq : Wv;
  #pragma unroll
  for (int g = 0; g < 4; g++) {
    f32x4_t acc = {0.f, 0.f, 0.f, 0.f};
    #pragma unroll
    for (int kh = 0; kh < 2; kh++) {
      bf16x8_t wf = cvtld8(W + (g * 16 + l15) * 64 + kh * 32 + quad * 8);
      acc = mfma16(xf[kh], wf, acc);
    }
    if (m == 0) {
      #pragma unroll
      for (int r = 0; r < 4; r++)
        ko[(long)(row0 + quad * 4 + r) * 64 + g * 16 + l15] = f2bf(acc[r]);
    } else if (m == 1) {
      #pragma unroll
      for (int r = 0; r < 4; r++)
        qo[(long)(row0 + quad * 4 + r) * 64 + g * 16 + l15] = f2bf(acc[r] * QSCALE);
    } else {
      #pragma unroll
      for (int r = 0; r < 4; r++)
        vTo[((long)b * 64 + g * 16 + l15) * Tt + rloc0 + quad * 4 + r] = f2bf(acc[r]);
    }
  }
}

// ---------------- flash v5: one block per q-64 tile, q=64/wave, 8-wave kv-parity ----------------
// 256 blocks x 512 thr (1 block/CU). qt descending so longest blocks dispatch first.
// Per tile (kv64 x q64): 16 global ld16 (16 KB) vs 72 MFMA -> L1 ~ MFMA balanced.
// exp2 via raw v_exp_f32; P packed by truncation (error cancels in P/l ratio).
// l via ones-MFMA. LDS 55 KB: pT [8][32][72]u16 (36864) overlaid after loop by
// chk [8][16][68]f32 (34816); stg [64][68]f32 @36864; lst [8][64]f32 @54272.
__global__ __launch_bounds__(512, 2) void HeadV1_flash(
    const u16* __restrict__ qg, const u16* __restrict__ kg,
    const u16* __restrict__ vTg, float* __restrict__ outg)
{
  __shared__ __align__(16) char smem[56320];
  u16  (*pT)[32][72]   = (u16 (*)[32][72])smem;
  float (*chk)[16][68] = (float (*)[16][68])smem;
  float (*stg)[68]     = (float (*)[68])(smem + 36864);
  float (*lst)[64]     = (float (*)[64])(smem + 54272);

  const int t    = threadIdx.x;
  const int w    = t >> 6;        // 0..7
  const int lane = t & 63;
  const int l15  = lane & 15;
  const int quad = lane >> 4;

  const int b  = blockIdx.x & 3;
  const int qt = 63 - (blockIdx.x >> 2);    // descending
  const int qr0 = qt * 64;
  const long base = (long)b * Tt * Dd;

  union { u32 u4[4]; bf16x8_t v; } uo;
  uo.u4[0] = uo.u4[1] = uo.u4[2] = uo.u4[3] = 0x3F803F80u; // bf16 1.0 x8
  const bf16x8_t ones = uo.v;
  const f32x4_t zero4 = {0.f, 0.f, 0.f, 0.f};

  // persistent Q B-fragments: 4 ct x 2 kk
  bf16x8_t qfrag[4][2];
  #pragma unroll
  for (int ct = 0; ct < 4; ct++)
    #pragma unroll
    for (int kk = 0; kk < 2; kk++)
      qfrag[ct][kk] = ld16(qg + base + (long)(qr0 + ct * 16 + l15) * 64 + kk * 32 + quad * 8);

  f32x4_t O[4][4];   // [dt][ct]
  #pragma unroll
  for (int a = 0; a < 4; a++)
    #pragma unroll
    for (int c = 0; c < 4; c++)
      O[a][c] = zero4;
  f32x4_t Lc[4] = {zero4, zero4, zero4, zero4};

  const int nk = qt + 1;

  for (int kt = w; kt < nk; kt += 8) {
    const int kv0 = kt * 64;
    const bool ismask = (kt == qt);

    // all 16 global loads up front: latency overlaps QK + exp2
    bf16x8_t kfrag[4][2];
    #pragma unroll
    for (int rt = 0; rt < 4; rt++)
      #pragma unroll
      for (int kk = 0; kk < 2; kk++)
        kfrag[rt][kk] = ld16(kg + base + (long)(kv0 + rt * 16 + l15) * 64 + kk * 32 + quad * 8);
    bf16x8_t vf[2][4];
    #pragma unroll
    for (int kk = 0; kk < 2; kk++)
      #pragma unroll
      for (int dt = 0; dt < 4; dt++)
        vf[kk][dt] = ld16(vTg + ((long)b * 64 + dt * 16 + l15) * Tt + kv0 + kk * 32 + quad * 8);

    #pragma unroll
    for (int half = 0; half < 2; half++) {
      // QK + exp2 + pack for ct = 2*half, 2*half+1 -> pT rows [0,32)
      #pragma unroll
      for (int rt = 0; rt < 4; rt++) {
        f32x4_t acc[2];
        #pragma unroll
        for (int cl = 0; cl < 2; cl++) {
          const int ct = half * 2 + cl;
          f32x4_t a = zero4;
          a = mfma16(kfrag[rt][0], qfrag[ct][0], a);
          a = mfma16(kfrag[rt][1], qfrag[ct][1], a);
          acc[cl] = a;
        }
        if (ismask) {
          const int kvl = rt * 16 + quad * 4;
          #pragma unroll
          for (int cl = 0; cl < 2; cl++) {
            const int ql = half * 32 + cl * 16 + l15;
            #pragma unroll
            for (int r = 0; r < 4; r++)
              if (kvl + r > ql) acc[cl][r] = -1e30f;  // v_exp -> 0
          }
        }
        #pragma unroll
        for (int cl = 0; cl < 2; cl++) {
          const float p0 = __builtin_amdgcn_exp2f(acc[cl][0]);
          const float p1 = __builtin_amdgcn_exp2f(acc[cl][1]);
          const float p2 = __builtin_amdgcn_exp2f(acc[cl][2]);
          const float p3 = __builtin_amdgcn_exp2f(acc[cl][3]);
          uint2 pk;
          pk.x = pkt(p0, p1);
          pk.y = pkt(p2, p3);
          *(uint2*)&pT[w][cl * 16 + l15][rt * 16 + quad * 4] = pk;
        }
      }
      // PV + l for this half (per-wave pT region: lgkmcnt only, no barrier)
      #pragma unroll
      for (int kk = 0; kk < 2; kk++) {
        bf16x8_t pf0 = ld16(&pT[w][l15][kk * 32 + quad * 8]);
        bf16x8_t pf1 = ld16(&pT[w][16 + l15][kk * 32 + quad * 8]);
        #pragma unroll
        for (int dt = 0; dt < 4; dt++) {
          O[dt][half * 2]     = mfma16(vf[kk][dt], pf0, O[dt][half * 2]);
          O[dt][half * 2 + 1] = mfma16(vf[kk][dt], pf1, O[dt][half * 2 + 1]);
        }
        Lc[half * 2]     = mfma16(ones, pf0, Lc[half * 2]);
        Lc[half * 2 + 1] = mfma16(ones, pf1, Lc[half * 2 + 1]);
      }
    }
  }

  // ---- 8-wave merge ----
  if (quad == 0) {
    #pragma unroll
    for (int ct = 0; ct < 4; ct++)
      lst[w][ct * 16 + l15] = Lc[ct][0];
  }
  __syncthreads();  // pT dead past here; chk overlays it

  #pragma unroll
  for (int dt = 0; dt < 4; dt++) {
    #pragma unroll
    for (int ct = 0; ct < 4; ct++)
      #pragma unroll
      for (int r = 0; r < 4; r++)
        chk[w][quad * 4 + r][ct * 16 + l15] = O[dt][ct][r];
    __syncthreads();
    #pragma unroll
    for (int h = 0; h < 2; h++) {
      const int pos = t + h * 512;   // 1024 cells: 16 d x 64 q
      const int d2 = pos >> 6, q = pos & 63;
      float s = 0.f;
      #pragma unroll
      for (int w2 = 0; w2 < 8; w2++) s += chk[w2][d2][q];
      stg[q][dt * 16 + d2] = s;
    }
    __syncthreads();
  }

  { // normalize + coalesced fp32 write: 64 q x 64 d
    const int q = t >> 3, d0 = (t & 7) * 8;
    float L = 0.f;
    #pragma unroll
    for (int w2 = 0; w2 < 8; w2++) L += lst[w2][q];
    const float invL = 1.0f / L;
    float ov[8];
    #pragma unroll
    for (int i = 0; i < 8; i++) ov[i] = stg[q][d0 + i] * invL;
    float* dst = outg + base + (long)(qr0 + q) * 64 + d0;
    *(float4*)dst       = *(const float4*)&ov[0];
    *(float4*)(dst + 4) = *(const float4*)&ov[4];
  }
}

extern "C" void kernel_launch(void* const* d_in, const int* in_sizes, int n_in,
                              void* d_out, int out_size, void* d_ws, size_t ws_size,
                              hipStream_t stream) {
  (void)in_sizes; (void)n_in; (void)out_size; (void)ws_size;
  const float* x  = (const float*)d_in[0];
  const float* Wk = (const float*)d_in[1];
  const float* Wq = (const float*)d_in[2];
  const float* Wv = (const float*)d_in[3];
  float* out = (float*)d_out;
  // workspace: q 2MB | k 2MB | vT 2MB
  u16* qw  = (u16*)d_ws;
  u16* kw  = qw + (size_t)Bb * Tt * Dd;
  u16* vTw = kw + (size_t)Bb * Tt * Dd;

  HeadV1_proj<<<dim3((Bb * Tt) / 64, 3), 256, 0, stream>>>(x, Wk, Wq, Wv, qw, kw, vTw);
  HeadV1_flash<<<256, 512, 0, stream>>>(qw, kw, vTw, out);
}

// Round 12
// 90.535 us; speedup vs baseline: 1.5989x; 1.1770x over previous
//
#include <hip/hip_runtime.h>
#include <hip/hip_bf16.h>

typedef unsigned short u16;
typedef unsigned int u32;
typedef __bf16 bf16x8_t __attribute__((ext_vector_type(8)));
typedef float f32x4_t __attribute__((ext_vector_type(4)));

constexpr int Bb = 4;
constexpr int Tt = 4096;
constexpr int Dd = 64;
constexpr float QSCALE = 0.18033688011112042f; // 0.125 * log2(e), folded into q

__device__ __forceinline__ u16 f2bf(float f) { // RNE
  unsigned int u = __builtin_bit_cast(unsigned int, f);
  return (u16)((u + 0x7fffu + ((u >> 16) & 1u)) >> 16);
}
__device__ __forceinline__ u32 pk2(float a, float b) { // RNE pack
  return (u32)f2bf(a) | ((u32)f2bf(b) << 16);
}
__device__ __forceinline__ u32 pkt(float a, float b) { // truncation pack (3 inst)
  const u32 ua = __builtin_bit_cast(u32, a);
  const u32 ub = __builtin_bit_cast(u32, b);
  return (ua >> 16) | (ub & 0xFFFF0000u);
}
__device__ __forceinline__ bf16x8_t ld16(const u16* p) {
  int4 v = *(const int4*)p;
  return __builtin_bit_cast(bf16x8_t, v);
}
__device__ __forceinline__ bf16x8_t cvtld8(const float* p) {
  float4 a = ((const float4*)p)[0];
  float4 b = ((const float4*)p)[1];
  union { u32 u[4]; bf16x8_t v; } r;
  r.u[0] = pk2(a.x, a.y); r.u[1] = pk2(a.z, a.w);
  r.u[2] = pk2(b.x, b.y); r.u[3] = pk2(b.z, b.w);
  return r.v;
}
__device__ __forceinline__ f32x4_t mfma16(bf16x8_t a, bf16x8_t b, f32x4_t c) {
  return __builtin_amdgcn_mfma_f32_16x16x32_bf16(a, b, c, 0, 0, 0);
}

// ---------------- proj v3: emits q/k/v in PRE-SWIZZLED MFMA-fragment order ----------------
// Block = one 64-row tile (b, kt). Fragment layouts (all tiles 4096 u16 = 8 KB):
//   qS/kS tile (b*64+t): frag(rt|ct, kk) at (idx*2+kk)*512 + lane*8 u16,
//     element j = Y[row = idx*16 + (lane&15)][col = kk*32 + (lane>>4)*8 + j]
//   vS  tile (b*64+kt):  frag(kk, dt)    at (kk*4+dt)*512 + lane*8 u16,
//     element j = V[kv = kk*32 + (lane>>4)*8 + j][d = dt*16 + (lane&15)]
// Flash then loads EVERY fragment as base + lane*16B: fully coalesced, const offsets.
__global__ __launch_bounds__(256) void HeadV1_proj(
    const float* __restrict__ x, const float* __restrict__ Wk,
    const float* __restrict__ Wq, const float* __restrict__ Wv,
    u16* __restrict__ qS, u16* __restrict__ kS, u16* __restrict__ vS)
{
  __shared__ u16 ylds[64][72];   // padded: row stride 144 B (multiple of 16)

  const int t = threadIdx.x;
  const int w = t >> 6, lane = t & 63, l15 = lane & 15, quad = lane >> 4;
  const int r0 = blockIdx.x * 64;
  const int b  = r0 >> 12;
  const int kt = (r0 & 4095) >> 6;
  const long tilebase = ((long)(b * 64 + kt)) * 4096;

  bf16x8_t xf[2];
  #pragma unroll
  for (int kh = 0; kh < 2; kh++)
    xf[kh] = cvtld8(x + (long)(r0 + w * 16 + l15) * 64 + kh * 32 + quad * 8);

  const float* Ws[3] = {Wk, Wq, Wv};
  u16* dsts[3];
  dsts[0] = kS + tilebase; dsts[1] = qS + tilebase; dsts[2] = vS + tilebase;

  #pragma unroll
  for (int m = 0; m < 3; m++) {
    // C-frags: vals[g][r] = Y[w*16 + quad*4 + r][g*16 + l15]
    float vals[4][4];
    #pragma unroll
    for (int g = 0; g < 4; g++) {
      f32x4_t acc = {0.f, 0.f, 0.f, 0.f};
      #pragma unroll
      for (int kh = 0; kh < 2; kh++) {
        bf16x8_t wf = cvtld8(Ws[m] + (g * 16 + l15) * 64 + kh * 32 + quad * 8);
        acc = mfma16(xf[kh], wf, acc);
      }
      #pragma unroll
      for (int r = 0; r < 4; r++)
        vals[g][r] = (m == 1) ? acc[r] * QSCALE : acc[r];
    }
    // stage to LDS (bf16)
    #pragma unroll
    for (int g = 0; g < 4; g++)
      #pragma unroll
      for (int r = 0; r < 4; r++)
        ylds[w * 16 + quad * 4 + r][g * 16 + l15] = f2bf(vals[g][r]);
    __syncthreads();
    // swizzled coalesced stores
    if (m < 2) { // K/Q: wave w -> frag idx rt|ct = w
      #pragma unroll
      for (int kk = 0; kk < 2; kk++) {
        bf16x8_t f = ld16(&ylds[w * 16 + l15][kk * 32 + quad * 8]);
        *(int4*)(dsts[m] + (w * 2 + kk) * 512 + lane * 8) = __builtin_bit_cast(int4, f);
      }
    } else {     // V: wave w -> dt = w; column walk in LDS
      #pragma unroll
      for (int kk = 0; kk < 2; kk++) {
        u16 tmp[8];
        #pragma unroll
        for (int j = 0; j < 8; j++)
          tmp[j] = ylds[kk * 32 + quad * 8 + j][w * 16 + l15];
        *(int4*)(dsts[2] + (kk * 4 + w) * 512 + lane * 8) = *(const int4*)tmp;
      }
    }
    __syncthreads();
  }
}

// ---------------- flash v6: R11 structure, ALL loads coalesced via swizzled layouts ----------------
// 256 blocks x 512 thr (1 block/CU), qt descending. 8 waves kv-parity. exp2 raw, trunc pack,
// l via ones-MFMA. LDS 55 KB: pT [8][32][72]u16 (36864) overlaid after loop by
// chk [8][16][68]f32; stg [64][68]f32 @36864; lst [8][64]f32 @54272.
__global__ __launch_bounds__(512, 2) void HeadV1_flash(
    const u16* __restrict__ qS, const u16* __restrict__ kS,
    const u16* __restrict__ vS, float* __restrict__ outg)
{
  __shared__ __align__(16) char smem[56320];
  u16  (*pT)[32][72]   = (u16 (*)[32][72])smem;
  float (*chk)[16][68] = (float (*)[16][68])smem;
  float (*stg)[68]     = (float (*)[68])(smem + 36864);
  float (*lst)[64]     = (float (*)[64])(smem + 54272);

  const int t    = threadIdx.x;
  const int w    = t >> 6;        // 0..7
  const int lane = t & 63;
  const int l15  = lane & 15;
  const int quad = lane >> 4;

  const int b  = blockIdx.x & 3;
  const int qt = 63 - (blockIdx.x >> 2);    // descending (longest first)
  const int qr0 = qt * 64;
  const long base = (long)b * Tt * Dd;

  union { u32 u4[4]; bf16x8_t v; } uo;
  uo.u4[0] = uo.u4[1] = uo.u4[2] = uo.u4[3] = 0x3F803F80u; // bf16 1.0 x8
  const bf16x8_t ones = uo.v;
  const f32x4_t zero4 = {0.f, 0.f, 0.f, 0.f};

  // persistent Q fragments: one coalesced 16B load each
  const u16* qtile = qS + ((long)(b * 64 + qt)) * 4096 + lane * 8;
  bf16x8_t qfrag[4][2];
  #pragma unroll
  for (int ct = 0; ct < 4; ct++)
    #pragma unroll
    for (int kk = 0; kk < 2; kk++)
      qfrag[ct][kk] = ld16(qtile + (ct * 2 + kk) * 512);

  f32x4_t O[4][4];   // [dt][ct]
  #pragma unroll
  for (int a = 0; a < 4; a++)
    #pragma unroll
    for (int c = 0; c < 4; c++)
      O[a][c] = zero4;
  f32x4_t Lc[4] = {zero4, zero4, zero4, zero4};

  const int nk = qt + 1;

  for (int kt = w; kt < nk; kt += 8) {
    const bool ismask = (kt == qt);
    const u16* ktile = kS + ((long)(b * 64 + kt)) * 4096 + lane * 8;
    const u16* vtile = vS + ((long)(b * 64 + kt)) * 4096 + lane * 8;

    // all 16 tile loads up front — every one is base + lane*16B + const offset
    bf16x8_t kfrag[4][2];
    #pragma unroll
    for (int rt = 0; rt < 4; rt++)
      #pragma unroll
      for (int kk = 0; kk < 2; kk++)
        kfrag[rt][kk] = ld16(ktile + (rt * 2 + kk) * 512);
    bf16x8_t vf[2][4];
    #pragma unroll
    for (int kk = 0; kk < 2; kk++)
      #pragma unroll
      for (int dt = 0; dt < 4; dt++)
        vf[kk][dt] = ld16(vtile + (kk * 4 + dt) * 512);

    #pragma unroll
    for (int half = 0; half < 2; half++) {
      #pragma unroll
      for (int rt = 0; rt < 4; rt++) {
        f32x4_t acc[2];
        #pragma unroll
        for (int cl = 0; cl < 2; cl++) {
          const int ct = half * 2 + cl;
          f32x4_t a = zero4;
          a = mfma16(kfrag[rt][0], qfrag[ct][0], a);
          a = mfma16(kfrag[rt][1], qfrag[ct][1], a);
          acc[cl] = a;
        }
        if (ismask) {
          const int kvl = rt * 16 + quad * 4;
          #pragma unroll
          for (int cl = 0; cl < 2; cl++) {
            const int ql = half * 32 + cl * 16 + l15;
            #pragma unroll
            for (int r = 0; r < 4; r++)
              if (kvl + r > ql) acc[cl][r] = -1e30f;  // v_exp -> 0
          }
        }
        #pragma unroll
        for (int cl = 0; cl < 2; cl++) {
          const float p0 = __builtin_amdgcn_exp2f(acc[cl][0]);
          const float p1 = __builtin_amdgcn_exp2f(acc[cl][1]);
          const float p2 = __builtin_amdgcn_exp2f(acc[cl][2]);
          const float p3 = __builtin_amdgcn_exp2f(acc[cl][3]);
          uint2 pk;
          pk.x = pkt(p0, p1);
          pk.y = pkt(p2, p3);
          *(uint2*)&pT[w][cl * 16 + l15][rt * 16 + quad * 4] = pk;
        }
      }
      // PV + l for this half (per-wave pT region: lgkmcnt only, no barrier)
      #pragma unroll
      for (int kk = 0; kk < 2; kk++) {
        bf16x8_t pf0 = ld16(&pT[w][l15][kk * 32 + quad * 8]);
        bf16x8_t pf1 = ld16(&pT[w][16 + l15][kk * 32 + quad * 8]);
        #pragma unroll
        for (int dt = 0; dt < 4; dt++) {
          O[dt][half * 2]     = mfma16(vf[kk][dt], pf0, O[dt][half * 2]);
          O[dt][half * 2 + 1] = mfma16(vf[kk][dt], pf1, O[dt][half * 2 + 1]);
        }
        Lc[half * 2]     = mfma16(ones, pf0, Lc[half * 2]);
        Lc[half * 2 + 1] = mfma16(ones, pf1, Lc[half * 2 + 1]);
      }
    }
  }

  // ---- 8-wave merge ----
  if (quad == 0) {
    #pragma unroll
    for (int ct = 0; ct < 4; ct++)
      lst[w][ct * 16 + l15] = Lc[ct][0];
  }
  __syncthreads();  // pT dead past here; chk overlays it

  #pragma unroll
  for (int dt = 0; dt < 4; dt++) {
    #pragma unroll
    for (int ct = 0; ct < 4; ct++)
      #pragma unroll
      for (int r = 0; r < 4; r++)
        chk[w][quad * 4 + r][ct * 16 + l15] = O[dt][ct][r];
    __syncthreads();
    #pragma unroll
    for (int h = 0; h < 2; h++) {
      const int pos = t + h * 512;   // 1024 cells: 16 d x 64 q
      const int d2 = pos >> 6, q = pos & 63;
      float s = 0.f;
      #pragma unroll
      for (int w2 = 0; w2 < 8; w2++) s += chk[w2][d2][q];
      stg[q][dt * 16 + d2] = s;
    }
    __syncthreads();
  }

  { // normalize + coalesced fp32 write: 64 q x 64 d
    const int q = t >> 3, d0 = (t & 7) * 8;
    float L = 0.f;
    #pragma unroll
    for (int w2 = 0; w2 < 8; w2++) L += lst[w2][q];
    const float invL = 1.0f / L;
    float ov[8];
    #pragma unroll
    for (int i = 0; i < 8; i++) ov[i] = stg[q][d0 + i] * invL;
    float* dst = outg + base + (long)(qr0 + q) * 64 + d0;
    *(float4*)dst       = *(const float4*)&ov[0];
    *(float4*)(dst + 4) = *(const float4*)&ov[4];
  }
}

extern "C" void kernel_launch(void* const* d_in, const int* in_sizes, int n_in,
                              void* d_out, int out_size, void* d_ws, size_t ws_size,
                              hipStream_t stream) {
  (void)in_sizes; (void)n_in; (void)out_size; (void)ws_size;
  const float* x  = (const float*)d_in[0];
  const float* Wk = (const float*)d_in[1];
  const float* Wq = (const float*)d_in[2];
  const float* Wv = (const float*)d_in[3];
  float* out = (float*)d_out;
  // workspace: qS 2MB | kS 2MB | vS 2MB (all in MFMA-fragment order)
  u16* qw  = (u16*)d_ws;
  u16* kw  = qw + (size_t)Bb * Tt * Dd;
  u16* vw  = kw + (size_t)Bb * Tt * Dd;

  HeadV1_proj<<<(Bb * Tt) / 64, 256, 0, stream>>>(x, Wk, Wq, Wv, qw, kw, vw);
  HeadV1_flash<<<256, 512, 0, stream>>>(qw, kw, vw, out);
}